// Round 2
// baseline (483.514 us; speedup 1.0000x reference)
//
#include <hip/hip_runtime.h>

// GraphAttentionLayer v4: B=16, M=2048, F_IN=128, F_OUT=64, ALPHA=0.2
// out = elu( softmax_j( mask(adj, leaky_relu(f1_i + f2_j)) ) @ (h@W) )
// Algebra: h' = ((P @ h) @ W)/den, f1 = h@(W@a1), f2 = h@(W@a2).
//
// v4 = v2's occupancy shape (1024 blocks x 256 thr -> 4 independent 4-wave
// barrier groups per CU) + v3's proven pieces (register A-frag, swizzled
// double-buffered hT, one raw barrier/iter) + new VALU cuts:
//  - v_cvt_pk_bf16_f32 (1 instr per f32 pair) for staging and score packing.
//  - fused per-tile f2 from staging registers (v2 style; f2all dropped ->
//    no second h pass through L2).
//  - adj prefetch depth 3, h depth 1 (h L2-hot under XCD swizzle).
//  - bijective XCD swizzle: each XCD gets 128 consecutive logical blocks
//    = exactly 2 batches -> h working set 2 MB fits 4 MB XCD L2.
//  - epilogue uses fp32 W straight from global (L2-resident); Wl dropped.
// LDS ~20.5 KB/block.

#define M_     2048
#define FIN_   128
#define F_     64
#define ALPHA_ 0.2f
#define ROWS_  32
#define TS_    36      // hT token stride in u16 (72 B rows; rows 8 apart shift 16 banks)
#define WT_    132     // Tsum row stride in floats

typedef float  float4_ __attribute__((ext_vector_type(4)));
typedef short  short4_ __attribute__((ext_vector_type(4)));
typedef short  short8  __attribute__((ext_vector_type(8)));
typedef int    int4_   __attribute__((ext_vector_type(4)));
typedef unsigned int u32x4 __attribute__((ext_vector_type(4)));
typedef unsigned short u16;
typedef unsigned int   u32;

// packed f32x2 -> bf16x2 (RNE, same rounding as the old software f2bf)
static __device__ __forceinline__ u32 cvtpk(float lo, float hi) {
    u32 r;
    asm("v_cvt_pk_bf16_f32 %0, %1, %2" : "=v"(r) : "v"(lo), "v"(hi));
    return r;
}

__global__ __launch_bounds__(256, 4) void k_gat4(
    const float* __restrict__ h, const int* __restrict__ adj,
    const float* __restrict__ W, const float* __restrict__ a,
    float* __restrict__ out)
{
    __shared__ float a_s[2 * F_];            // 512 B
    __shared__ float wa1[FIN_], wa2[FIN_];   // 1 KB
    __shared__ float f1s[ROWS_];             // 128 B
    __shared__ float dens[ROWS_];            // 128 B
    __shared__ char  dyn[18688];             // loop buffers / Tsum (aliased)

    u16*   hTbuf0 = (u16*)dyn;               // [128][TS_] 9216 B
    u16*   hTbuf1 = (u16*)(dyn + 9216);      // [128][TS_] 9216 B
    float* f2t0   = (float*)(dyn + 18432);   // [32] 128 B
    float* f2t1   = (float*)(dyn + 18560);   // [32] 128 B
    float* Tsum   = (float*)dyn;             // [32][WT_] 16896 B (epilogue only)

    const int tid  = threadIdx.x;
    const int w    = tid >> 6;
    const int l    = tid & 63;
    const int lc   = l & 15;
    const int quad = l >> 4;

    // bijective XCD swizzle (1024 % 8 == 0): XCD x gets logical 128x..128x+127
    const u32 bid = blockIdx.x;
    const u32 lg  = (bid & 7) * 128 + (bid >> 3);
    const int b   = lg >> 6;
    const int i0  = (lg & 63) * ROWS_;

    const int rg = w & 1;            // wave row half (16 rows)
    const int nh = w >> 1;           // wave feature half (4 of 8 N-tiles)
    const int fo = tid & 15;         // staging: feature octet
    const int tp = tid >> 4;         // staging: token pair (2tp, 2tp+1)

    // ---------------- stage a ------------------------------------------------
    if (tid < 128) a_s[tid] = a[tid];
    __syncthreads();

    // ---------------- wa1/wa2 = W @ a1, W @ a2 (fp32) ------------------------
    if (tid < FIN_) {
        float s1 = 0.f, s2 = 0.f;
#pragma unroll 8
        for (int n = 0; n < F_; ++n) {
            float wv = W[tid * F_ + n];
            s1 += wv * a_s[n];
            s2 += wv * a_s[F_ + n];
        }
        wa1[tid] = s1;
        wa2[tid] = s2;
    }
    __syncthreads();

    // ---------------- f1 for this block's 32 rows ----------------------------
    {
        const int r = tid >> 3, k0 = (tid & 7) * 16;
        const float* hp = h + ((size_t)(b * M_ + i0 + r)) * FIN_ + k0;
        float s = 0.f;
#pragma unroll
        for (int k = 0; k < 16; ++k) s += hp[k] * wa1[k0 + k];
        s += __shfl_xor(s, 1, 64);
        s += __shfl_xor(s, 2, 64);
        s += __shfl_xor(s, 4, 64);
        if ((tid & 7) == 0) f1s[r] = s;
    }

    // hoisted wa2 octet for the fused f2 partials (wa2 synced above)
    float4_ w2a = *(const float4_*)(wa2 + fo * 8);
    float4_ w2b = *(const float4_*)(wa2 + fo * 8 + 4);

    const int*   aprow  = adj + ((size_t)(b * M_ + i0 + rg * 16 + lc)) * M_ + quad * 8;
    const float* hstage = h + ((size_t)(b * M_ + 2 * tp)) * FIN_ + fo * 8;

    // prologue prefetch: adj tiles 0..2 (depth 3), h tile 0
    int4_   aA0 = *(const int4_*)(aprow);
    int4_   aA1 = *(const int4_*)(aprow + 4);
    int4_   aB0 = *(const int4_*)(aprow + 32);
    int4_   aB1 = *(const int4_*)(aprow + 36);
    int4_   aC0 = *(const int4_*)(aprow + 64);
    int4_   aC1 = *(const int4_*)(aprow + 68);
    float4_ hE0 = *(const float4_*)(hstage);
    float4_ hE1 = *(const float4_*)(hstage + 4);
    float4_ hO0 = *(const float4_*)(hstage + FIN_);
    float4_ hO1 = *(const float4_*)(hstage + FIN_ + 4);

    __syncthreads();   // f1s ready

    const float f1r = f1s[rg * 16 + lc];
    float denacc = 0.f;
    float4_ acc0 = {0.f,0.f,0.f,0.f}, acc1 = {0.f,0.f,0.f,0.f};
    float4_ acc2 = {0.f,0.f,0.f,0.f}, acc3 = {0.f,0.f,0.f,0.f};

#pragma unroll 2
    for (int t = 0; t < 64; ++t) {
        u16*   hT  = (t & 1) ? hTbuf1 : hTbuf0;
        float* f2c = (t & 1) ? f2t1   : f2t0;
        const int jn = (t < 63 ? t + 1 : 63) * 32;   // h prefetch (depth 1)
        const int jp = (t < 61 ? t + 3 : 63) * 32;   // adj prefetch (depth 3)

        // ---- issue prefetches; stay in flight across the raw barrier ----
        int4_   nA0 = *(const int4_*)(aprow + jp);
        int4_   nA1 = *(const int4_*)(aprow + jp + 4);
        float4_ nE0 = *(const float4_*)(hstage + (size_t)jn * FIN_);
        float4_ nE1 = *(const float4_*)(hstage + (size_t)jn * FIN_ + 4);
        float4_ nO0 = *(const float4_*)(hstage + (size_t)jn * FIN_ + FIN_);
        float4_ nO1 = *(const float4_*)(hstage + (size_t)jn * FIN_ + FIN_ + 4);

        // ---- stage hT tile (bf16 token-pairs, swizzled slots) + fused f2 ----
        // slot = tp ^ ((k>>3)&12) is constant per thread (k>>3 == fo).
        {
            u16* wbase = hT + fo * (8 * TS_) + 2 * (tp ^ (fo & 12));
            float fp0 = 0.f, fp1 = 0.f;
#pragma unroll
            for (int kk = 0; kk < 8; ++kk) {
                float ev = (kk < 4) ? hE0[kk] : hE1[kk - 4];
                float od = (kk < 4) ? hO0[kk] : hO1[kk - 4];
                *(u32*)(wbase + kk * TS_) = cvtpk(ev, od);
                float wk = (kk < 4) ? w2a[kk] : w2b[kk - 4];
                fp0 += ev * wk;
                fp1 += od * wk;
            }
            fp0 += __shfl_xor(fp0, 1, 64); fp1 += __shfl_xor(fp1, 1, 64);
            fp0 += __shfl_xor(fp0, 2, 64); fp1 += __shfl_xor(fp1, 2, 64);
            fp0 += __shfl_xor(fp0, 4, 64); fp1 += __shfl_xor(fp1, 4, 64);
            fp0 += __shfl_xor(fp0, 8, 64); fp1 += __shfl_xor(fp1, 8, 64);
            if (fo == 0) { f2c[2 * tp] = fp0; f2c[2 * tp + 1] = fp1; }
        }

        // producer drain + raw barrier (NO vmcnt drain -> prefetches live on)
        asm volatile("s_waitcnt lgkmcnt(0)" ::: "memory");
        __builtin_amdgcn_s_barrier();
        __builtin_amdgcn_sched_barrier(0);

        // ---- scores for (row, tokens quad*8..+7): A-frag in registers ----
        float4_ g0 = *(const float4_*)(f2c + quad * 8);
        float4_ g1 = *(const float4_*)(f2c + quad * 8 + 4);
        u32x4 pw;
        float d = 0.f;
#define SC(GE, GO, AE, AO, IDX)                                 \
        {                                                       \
            float xe = f1r + (GE); xe = fmaxf(xe, ALPHA_ * xe); \
            float xo = f1r + (GO); xo = fmaxf(xo, ALPHA_ * xo); \
            float ee = ((AE) > 0) ? __expf(xe) : 0.f;           \
            float eo = ((AO) > 0) ? __expf(xo) : 0.f;           \
            u32 pk = cvtpk(ee, eo);                             \
            d += __uint_as_float(pk << 16);                     \
            d += __uint_as_float(pk & 0xFFFF0000u);             \
            pw[IDX] = pk;                                       \
        }
        SC(g0[0], g0[1], aA0[0], aA0[1], 0)
        SC(g0[2], g0[3], aA0[2], aA0[3], 1)
        SC(g1[0], g1[1], aA1[0], aA1[1], 2)
        SC(g1[2], g1[3], aA1[2], aA1[3], 3)
#undef SC
        denacc += d;
        short8 af = __builtin_bit_cast(short8, pw);

        // ---- MFMA: 4 feature tiles of this wave's half; B de-swizzled ----
#define MT(C, ACC)                                                             \
        {                                                                      \
            const u16* bp = hT + ((nh * 4 + (C)) * 16 + lc) * TS_              \
                          + (((quad * 4) ^ (((nh * 4 + (C)) * 2) & 12)) << 1); \
            short4_ b0 = *(const short4_*)bp;                                  \
            short4_ b1 = *(const short4_*)(bp + 4);                            \
            short8 bf;                                                         \
            bf[0] = b0[0]; bf[1] = b0[1]; bf[2] = b0[2]; bf[3] = b0[3];        \
            bf[4] = b1[0]; bf[5] = b1[1]; bf[6] = b1[2]; bf[7] = b1[3];        \
            ACC = __builtin_amdgcn_mfma_f32_16x16x32_bf16(af, bf, ACC, 0, 0, 0); \
        }
        MT(0, acc0) MT(1, acc1) MT(2, acc2) MT(3, acc3)
#undef MT

        // rotate prefetch registers
        aA0 = aB0; aA1 = aB1; aB0 = aC0; aB1 = aC1; aC0 = nA0; aC1 = nA1;
        hE0 = nE0; hE1 = nE1; hO0 = nO0; hO1 = nO1;
    }

    // ---------------- denom: reduce over the 4 quads -------------------------
    denacc += __shfl_xor(denacc, 16, 64);
    denacc += __shfl_xor(denacc, 32, 64);
    if (nh == 0 && quad == 0) dens[rg * 16 + lc] = denacc;
    __syncthreads();   // all hT/f2t reads done; Tsum alias safe

    // ---------------- T -> LDS (disjoint per wave) ---------------------------
#pragma unroll
    for (int mm = 0; mm < 4; ++mm) {
        float* tr = Tsum + (rg * 16 + quad * 4 + mm) * WT_ + nh * 64 + lc;
        tr[0]  = acc0[mm];
        tr[16] = acc1[mm];
        tr[32] = acc2[mm];
        tr[48] = acc3[mm];
    }
    __syncthreads();

    // ---------------- epilogue: out = elu( (T @ W_fp32) / den ) --------------
    {
        const int r  = tid >> 3;
        const int n0 = (tid & 7) * 8;
        const float den  = dens[r];
        const float rden = (den > 0.f) ? (1.f / den) : 0.f;
        float u[8];
#pragma unroll
        for (int nn = 0; nn < 8; ++nn) u[nn] = 0.f;
#pragma unroll 4
        for (int k = 0; k < FIN_; ++k) {
            const float tv = Tsum[r * WT_ + k];
            float4_ wv0 = *(const float4_*)(W + k * F_ + n0);
            float4_ wv1 = *(const float4_*)(W + k * F_ + n0 + 4);
            u[0] += tv * wv0[0]; u[1] += tv * wv0[1];
            u[2] += tv * wv0[2]; u[3] += tv * wv0[3];
            u[4] += tv * wv1[0]; u[5] += tv * wv1[1];
            u[6] += tv * wv1[2]; u[7] += tv * wv1[3];
        }
        float4_ o0, o1;
#pragma unroll
        for (int nn = 0; nn < 8; ++nn) {
            float hp = u[nn] * rden;
            float o  = hp > 0.f ? hp : expm1f(hp);
            if (nn < 4) o0[nn] = o; else o1[nn - 4] = o;
        }
        float* op = out + ((size_t)(b * M_ + i0 + r)) * F_ + n0;
        *(float4_*)op       = o0;
        *(float4_*)(op + 4) = o1;
    }
}

// ---------------------------------------------------------------------------
extern "C" void kernel_launch(void* const* d_in, const int* in_sizes, int n_in,
                              void* d_out, int out_size, void* d_ws, size_t ws_size,
                              hipStream_t stream)
{
    (void)out_size; (void)d_ws; (void)ws_size;
    const float* h  = (const float*)d_in[0];
    const int* adjp = (const int*)d_in[1];
    const float* Wp = (const float*)d_in[2];
    const float* ap = (const float*)d_in[3];
    for (int i = 0; i < n_in; ++i) {
        long s = in_sizes[i];
        if      (s == 4194304L)  h    = (const float*)d_in[i];
        else if (s == 67108864L) adjp = (const int*)d_in[i];
        else if (s == 8192L)     Wp   = (const float*)d_in[i];
        else if (s == 128L)      ap   = (const float*)d_in[i];
    }
    k_gat4<<<1024, 256, 0, stream>>>(h, adjp, Wp, ap, (float*)d_out);
}

// Round 3
// 427.968 us; speedup vs baseline: 1.1298x; 1.1298x over previous
//
#include <hip/hip_runtime.h>

// GraphAttentionLayer v5: B=16, M=2048, F_IN=128, F_OUT=64, ALPHA=0.2
// out = elu( softmax_j( mask(adj, leaky_relu(f1_i + f2_j)) ) @ (h@W) )
// Algebra: h' = ((P @ h) @ W)/den, f1 = h@(W@a1), f2 = h@(W@a2).
//
// v5 = two plain dispatches on one stream (single kernel_launch call):
//  k_prep: h -> hbf (bf16, MFMA-B-fragment-linear [b][tile][nt][lane]x16B)
//          + f1all/f2all (fp32 per token). Runs ONCE; deletes the per-block
//          h-conversion redundancy that kept v2-v4 VALU-heavy (64x per batch).
//  k_main: zero barriers in the main loop. Each wave owns 16 rows x 128 feats.
//          Per iter: 2 adj loads (HBM stream, depth-3 reg prefetch),
//          8 B-frag loads (L2-hot hbf, depth-1), 2 LDS broadcast f2 reads,
//          8 exp, 8 MFMA. No staging, no inter-wave coupling, no duplication.
// d_ws: hbf 8 MB + f1all 128 KB + f2all 128 KB (within-call handoff only).

#define M_     2048
#define FIN_   128
#define F_     64
#define ALPHA_ 0.2f
#define HS_    132     // k_prep LDS h-tile stride (floats)
#define WT_    132     // Tsum row stride (floats)

typedef float  float4_ __attribute__((ext_vector_type(4)));
typedef short  short8  __attribute__((ext_vector_type(8)));
typedef int    int4_   __attribute__((ext_vector_type(4)));
typedef unsigned int u32x4 __attribute__((ext_vector_type(4)));
typedef unsigned short u16;
typedef unsigned int   u32;

// packed f32x2 -> bf16x2 (RNE)
static __device__ __forceinline__ u32 cvtpk(float lo, float hi) {
    u32 r;
    asm("v_cvt_pk_bf16_f32 %0, %1, %2" : "=v"(r) : "v"(lo), "v"(hi));
    return r;
}

// ---------------------------------------------------------------------------
// Phase 1: hbf fragment layout: ((b*64 + t)*8 + nt)*64 + l  (16B per entry)
//   lane l of a wave holds B[n = nt*16 + (l&15)][k = (l>>4)*8 .. +7]
//   (tokens packed pairwise: u32 = bf16(tok_even) | bf16(tok_odd)<<16)
// ---------------------------------------------------------------------------
__global__ __launch_bounds__(256, 4) void k_prep(
    const float* __restrict__ h, const float* __restrict__ W,
    const float* __restrict__ a, u16* __restrict__ hbf,
    float* __restrict__ f1all, float* __restrict__ f2all)
{
    __shared__ float a_s[2 * F_];
    __shared__ float wa1[FIN_], wa2[FIN_];
    __shared__ float hs[32 * HS_];

    const int tid = threadIdx.x;
    const u32 bid = blockIdx.x;
    const u32 lg  = (bid & 7) * 128 + (bid >> 3);   // XCD x produces batches 2x,2x+1
    const int b   = lg >> 6;
    const int t   = lg & 63;

    if (tid < 128) a_s[tid] = a[tid];

    // h tile -> regs (coalesced float4)
    const int tok = tid >> 3, f0 = (tid & 7) * 16;
    const float* hp = h + ((size_t)(b * M_ + t * 32 + tok)) * FIN_ + f0;
    float4_ x0 = *(const float4_*)hp;
    float4_ x1 = *(const float4_*)(hp + 4);
    float4_ x2 = *(const float4_*)(hp + 8);
    float4_ x3 = *(const float4_*)(hp + 12);
    __syncthreads();   // a_s ready

    if (tid < FIN_) {
        float s1 = 0.f, s2 = 0.f;
#pragma unroll 8
        for (int n = 0; n < F_; ++n) {
            float wv = W[tid * F_ + n];
            s1 += wv * a_s[n];
            s2 += wv * a_s[F_ + n];
        }
        wa1[tid] = s1;
        wa2[tid] = s2;
    }

    float* hr = hs + tok * HS_ + f0;
    *(float4_*)(hr)      = x0;
    *(float4_*)(hr + 4)  = x1;
    *(float4_*)(hr + 8)  = x2;
    *(float4_*)(hr + 12) = x3;
    __syncthreads();   // hs + wa ready

    // ---- fragment conversion: thread handles lane l for nt0, nt0+1 ----
    {
        const int l = tid & 63, lc = l & 15, q = l >> 4;
        const int nt0 = (tid >> 6) * 2;
        u32x4* ob = (u32x4*)hbf + ((size_t)(b * 64 + t)) * 8 * 64;
#pragma unroll
        for (int ni = 0; ni < 2; ++ni) {
            const int nt = nt0 + ni;
            const float* cp = hs + (q * 8) * HS_ + nt * 16 + lc;
            u32x4 wv;
            wv[0] = cvtpk(cp[0 * HS_], cp[1 * HS_]);
            wv[1] = cvtpk(cp[2 * HS_], cp[3 * HS_]);
            wv[2] = cvtpk(cp[4 * HS_], cp[5 * HS_]);
            wv[3] = cvtpk(cp[6 * HS_], cp[7 * HS_]);
            ob[nt * 64 + l] = wv;
        }
    }

    // ---- f1/f2 per token (same order as v4's f1 tree) ----
    {
        const int r = tid >> 3, k0 = (tid & 7) * 16;
        const float* rp = hs + r * HS_ + k0;
        float s1 = 0.f, s2 = 0.f;
#pragma unroll
        for (int k = 0; k < 16; ++k) {
            s1 += rp[k] * wa1[k0 + k];
            s2 += rp[k] * wa2[k0 + k];
        }
        s1 += __shfl_xor(s1, 1, 64); s2 += __shfl_xor(s2, 1, 64);
        s1 += __shfl_xor(s1, 2, 64); s2 += __shfl_xor(s2, 2, 64);
        s1 += __shfl_xor(s1, 4, 64); s2 += __shfl_xor(s2, 4, 64);
        if ((tid & 7) == 0) {
            f1all[b * M_ + t * 32 + r] = s1;
            f2all[b * M_ + t * 32 + r] = s2;
        }
    }
}

// ---------------------------------------------------------------------------
// Phase 2: 512 blocks x 256 thr. Block = 64 rows (4 waves x 16 rows), full
// feature width per wave. Zero barriers in the 64-iter token loop.
// ---------------------------------------------------------------------------
__global__ __launch_bounds__(256, 2) void k_main(
    const int* __restrict__ adj, const u16* __restrict__ hbf,
    const float* __restrict__ f1all, const float* __restrict__ f2all,
    const float* __restrict__ W, float* __restrict__ out)
{
    __shared__ char  dyn[WT_ * 64 * 4];   // f2s (8 KB) then Tsum (33.8 KB)
    __shared__ float dens[64];

    float* f2s  = (float*)dyn;
    float* Tsum = (float*)dyn;

    const int tid  = threadIdx.x;
    const int w    = tid >> 6;
    const int l    = tid & 63;
    const int lc   = l & 15;
    const int quad = l >> 4;

    const u32 bid = blockIdx.x;
    const u32 lg  = (bid & 7) * 64 + (bid >> 3);    // XCD x consumes batches 2x,2x+1
    const int b   = lg >> 5;
    const int i0  = (lg & 31) * 64;
    const int rowbase = i0 + w * 16;

    // stage f2all[b] -> LDS (8 KB, broadcast-read in loop)
    {
        const int o = tid * 8;
        float4_ v0 = *(const float4_*)(f2all + b * M_ + o);
        float4_ v1 = *(const float4_*)(f2all + b * M_ + o + 4);
        *(float4_*)(f2s + o)     = v0;
        *(float4_*)(f2s + o + 4) = v1;
    }

    const float f1r = f1all[b * M_ + rowbase + lc];
    const int* aprow = adj + ((size_t)(b * M_ + rowbase + lc)) * M_ + quad * 8;
    const u32x4* hb  = (const u32x4*)hbf + ((size_t)b * 64) * 8 * 64 + l;

    // prologue: adj depth 3, hbf tile 0
    int4_ aA0 = *(const int4_*)(aprow);
    int4_ aA1 = *(const int4_*)(aprow + 4);
    int4_ aB0 = *(const int4_*)(aprow + 32);
    int4_ aB1 = *(const int4_*)(aprow + 36);
    int4_ aC0 = *(const int4_*)(aprow + 64);
    int4_ aC1 = *(const int4_*)(aprow + 68);
    u32x4 bC[8];
#pragma unroll
    for (int nt = 0; nt < 8; ++nt) bC[nt] = hb[nt * 64];

    __syncthreads();   // f2s ready

    float denacc = 0.f;
    float4_ acc[8];
#pragma unroll
    for (int nt = 0; nt < 8; ++nt) acc[nt] = (float4_){0.f, 0.f, 0.f, 0.f};

#pragma unroll 2
    for (int t = 0; t < 64; ++t) {
        const int jp = (t < 61 ? t + 3 : 63) * 32;   // adj prefetch (depth 3)
        const int tn = (t < 63 ? t + 1 : 63);        // hbf prefetch (depth 1)

        // issue prefetches first (independent of this iter's consumers)
        int4_ nA0 = *(const int4_*)(aprow + jp);
        int4_ nA1 = *(const int4_*)(aprow + jp + 4);
        u32x4 bN[8];
#pragma unroll
        for (int nt = 0; nt < 8; ++nt) bN[nt] = hb[(tn * 8 + nt) * 64];

        // f2 for this tile's 8 tokens (LDS broadcast within each quad)
        float4_ g0 = *(const float4_*)(f2s + t * 32 + quad * 8);
        float4_ g1 = *(const float4_*)(f2s + t * 32 + quad * 8 + 4);

        // scores -> A-frag (rounded-P den, identical numerics to v4)
        u32x4 pw;
        float d = 0.f;
#define SC(GE, GO, AE, AO, IDX)                                 \
        {                                                       \
            float xe = f1r + (GE); xe = fmaxf(xe, ALPHA_ * xe); \
            float xo = f1r + (GO); xo = fmaxf(xo, ALPHA_ * xo); \
            float ee = ((AE) > 0) ? __expf(xe) : 0.f;           \
            float eo = ((AO) > 0) ? __expf(xo) : 0.f;           \
            u32 pk = cvtpk(ee, eo);                             \
            d += __uint_as_float(pk << 16);                     \
            d += __uint_as_float(pk & 0xFFFF0000u);             \
            pw[IDX] = pk;                                       \
        }
        SC(g0[0], g0[1], aA0[0], aA0[1], 0)
        SC(g0[2], g0[3], aA0[2], aA0[3], 1)
        SC(g1[0], g1[1], aA1[0], aA1[1], 2)
        SC(g1[2], g1[3], aA1[2], aA1[3], 3)
#undef SC
        denacc += d;
        const short8 af = __builtin_bit_cast(short8, pw);

        // 8 MFMAs: full feature width for this wave's 16 rows
#pragma unroll
        for (int nt = 0; nt < 8; ++nt)
            acc[nt] = __builtin_amdgcn_mfma_f32_16x16x32_bf16(
                af, __builtin_bit_cast(short8, bC[nt]), acc[nt], 0, 0, 0);

        // rotate prefetch registers
        aA0 = aB0; aA1 = aB1; aB0 = aC0; aB1 = aC1; aC0 = nA0; aC1 = nA1;
#pragma unroll
        for (int nt = 0; nt < 8; ++nt) bC[nt] = bN[nt];
    }

    // ---- denom: reduce over the 4 quads ----
    denacc += __shfl_xor(denacc, 16, 64);
    denacc += __shfl_xor(denacc, 32, 64);
    if (quad == 0) dens[w * 16 + lc] = denacc;
    __syncthreads();   // f2s dead; Tsum alias safe

    // ---- T -> LDS (disjoint per wave; 2-way banks = free) ----
#pragma unroll
    for (int nt = 0; nt < 8; ++nt)
#pragma unroll
        for (int mm = 0; mm < 4; ++mm)
            Tsum[(w * 16 + quad * 4 + mm) * WT_ + nt * 16 + lc] = acc[nt][mm];
    __syncthreads();

    // ---- epilogue: out = elu( (T @ W_fp32) / den ), 64 rows in 2 passes ----
#pragma unroll
    for (int rr = 0; rr < 2; ++rr) {
        const int r  = (tid >> 3) + rr * 32;
        const int n0 = (tid & 7) * 8;
        const float den  = dens[r];
        const float rden = (den > 0.f) ? (1.f / den) : 0.f;
        float u[8];
#pragma unroll
        for (int nn = 0; nn < 8; ++nn) u[nn] = 0.f;
#pragma unroll 4
        for (int k = 0; k < FIN_; ++k) {
            const float tv = Tsum[r * WT_ + k];
            float4_ wv0 = *(const float4_*)(W + k * F_ + n0);
            float4_ wv1 = *(const float4_*)(W + k * F_ + n0 + 4);
            u[0] += tv * wv0[0]; u[1] += tv * wv0[1];
            u[2] += tv * wv0[2]; u[3] += tv * wv0[3];
            u[4] += tv * wv1[0]; u[5] += tv * wv1[1];
            u[6] += tv * wv1[2]; u[7] += tv * wv1[3];
        }
        float4_ o0, o1;
#pragma unroll
        for (int nn = 0; nn < 8; ++nn) {
            float hp = u[nn] * rden;
            float o  = hp > 0.f ? hp : expm1f(hp);
            if (nn < 4) o0[nn] = o; else o1[nn - 4] = o;
        }
        float* op = out + ((size_t)(b * M_ + i0 + r)) * F_ + n0;
        *(float4_*)op       = o0;
        *(float4_*)(op + 4) = o1;
    }
}

// ---------------------------------------------------------------------------
extern "C" void kernel_launch(void* const* d_in, const int* in_sizes, int n_in,
                              void* d_out, int out_size, void* d_ws, size_t ws_size,
                              hipStream_t stream)
{
    (void)out_size; (void)ws_size;
    const float* h  = (const float*)d_in[0];
    const int* adjp = (const int*)d_in[1];
    const float* Wp = (const float*)d_in[2];
    const float* ap = (const float*)d_in[3];
    for (int i = 0; i < n_in; ++i) {
        long s = in_sizes[i];
        if      (s == 4194304L)  h    = (const float*)d_in[i];
        else if (s == 67108864L) adjp = (const int*)d_in[i];
        else if (s == 8192L)     Wp   = (const float*)d_in[i];
        else if (s == 128L)      ap   = (const float*)d_in[i];
    }
    u16*   hbf   = (u16*)d_ws;                                  // 8 MB
    float* f1all = (float*)((char*)d_ws + (8u << 20));          // 128 KB
    float* f2all = f1all + 16 * M_;                             // 128 KB
    k_prep<<<1024, 256, 0, stream>>>(h, Wp, ap, hbf, f1all, f2all);
    k_main<<<512, 256, 0, stream>>>(adjp, hbf, f1all, f2all, Wp, (float*)d_out);
}